// Round 5
// baseline (23793.716 us; speedup 1.0000x reference)
//
#include <hip/hip_runtime.h>
#include <hip/hip_bf16.h>
#include <stdint.h>

// GRU B=64 T=512 I=512 H=1024, fp32 in/out.
// bf16 hi/lo 3-pass MFMA numerics.
// Round 5: same persistent structure as round 4, but ALL coherent (sc0sc1)
// producer stores vectorized to dwordx4 via 128 storer-lanes/wg (8 cols each)
// -> 1-2 coherent store instrs per wave instead of 32-64 (tests the theory
// that the per-step constant is the sc-store drain). h fp32 array dropped
// from the critical path (A-r reconstructs h = hi+lo from h2).

#define B_ 64
#define T_ 512
#define I_ 512
#define H_ 1024
#define NWG_A 128
#define NWG_B 64
#define NWG 192
#define FSTR 64   // flag padding stride (uints) = 256B

typedef __attribute__((ext_vector_type(4))) float f32x4;
typedef __attribute__((ext_vector_type(8))) short s16x8;

__device__ __forceinline__ unsigned short f2bf(float f) {
  union { float f; uint32_t u; } v; v.f = f;
  uint32_t u = v.u;
  u += 0x7fffu + ((u >> 16) & 1u);   // RNE
  return (unsigned short)(u >> 16);
}
__device__ __forceinline__ float bf2f(unsigned short h) {
  union { uint32_t u; float f; } v; v.u = ((uint32_t)h) << 16;
  return v.f;
}

// ---- coherent write-through stores (visible at coherence point) ----
__device__ __forceinline__ void sc_store_b128(uint16_t* p, s16x8 v) {
  asm volatile("global_store_dwordx4 %0, %1, off sc0 sc1"
               :: "v"(p), "v"(v) : "memory");
}
__device__ __forceinline__ void sc_store_f32x4(float* p, f32x4 v) {
  asm volatile("global_store_dwordx4 %0, %1, off sc0 sc1"
               :: "v"(p), "v"(v) : "memory");
}
__device__ __forceinline__ void sc_store_u32(unsigned* p, unsigned v) {
  asm volatile("global_store_dword %0, %1, off sc0 sc1"
               :: "v"(p), "v"(v) : "memory");
}
// ---- L2-cached consumer loads (fresh after agent-acquire buffer_inv) ----
__device__ __forceinline__ s16x8 sc0_load_b128(const uint16_t* p) {
  s16x8 r;
  asm volatile("global_load_dwordx4 %0, %1, off sc0"
               : "=v"(r) : "v"(p) : "memory");
  return r;
}
__device__ __forceinline__ f32x4 sc0_load_f32x4(const float* p) {
  f32x4 r;
  asm volatile("global_load_dwordx4 %0, %1, off sc0"
               : "=v"(r) : "v"(p) : "memory");
  return r;
}
__device__ __forceinline__ void vm_drain() {
  asm volatile("s_waitcnt vmcnt(0)" ::: "memory");
}

// src [N][K] fp32 -> dst [N][3K] bf16 as [hi | lo | hi] K-blocks. K = 1<<kshift.
__global__ void k_split(const float* __restrict__ src, uint16_t* __restrict__ dst,
                        int kshift, int total) {
  int K = 1 << kshift;
  for (int i = blockIdx.x * blockDim.x + threadIdx.x; i < total;
       i += gridDim.x * blockDim.x) {
    int n = i >> kshift, k = i & (K - 1);
    float f = src[i];
    unsigned short hi = f2bf(f);
    unsigned short lo = f2bf(f - bf2f(hi));
    size_t base = (size_t)n * (3 * K);
    dst[base + k] = hi;
    dst[base + K + k] = lo;
    dst[base + 2 * K + k] = hi;
  }
}

__global__ void k_init(const float* __restrict__ h0, float* __restrict__ h,
                       uint16_t* __restrict__ h2) {
  for (int i = blockIdx.x * blockDim.x + threadIdx.x; i < B_ * H_;
       i += gridDim.x * blockDim.x) {
    float f = h0[i];
    h[i] = f;
    int b = i >> 10, j = i & 1023;
    unsigned short hi = f2bf(f);
    h2[b * 2048 + j] = hi;
    h2[b * 2048 + 1024 + j] = f2bf(f - bf2f(hi));
  }
}

// Projection GEMM (unchanged): XP[tt][gate][b][j] = x@W^T + bias
__global__ __launch_bounds__(256) void k_proj(
    const float* __restrict__ x, const uint16_t* __restrict__ W2,
    const float* __restrict__ bz, const float* __restrict__ br,
    const float* __restrict__ bh,
    float* __restrict__ XP, int t0, int Tc, int MT) {
  __shared__ uint16_t As[128][72];
  __shared__ uint16_t Bs[128][72];
  int bid = blockIdx.x;
  int mt = bid % MT, nt = bid / MT;
  int tid = threadIdx.x;
  int w = tid >> 6, l = tid & 63;
  int wm = w >> 1, wn = w & 1;
  int lr = l & 15, lg = l >> 4;

  int gr[4], gc8[4];
  const float* asrc[4];
  const uint16_t* bsrc[4];
#pragma unroll
  for (int g = 0; g < 4; ++g) {
    int gran = tid + 256 * g;
    int r = gran >> 3, c8 = gran & 7;
    gr[g] = r; gc8[g] = c8;
    int n = mt * 128 + r;
    int b = n / Tc, tt = n % Tc;
    asrc[g] = x + ((size_t)b * T_ + (t0 + tt)) * I_;
    bsrc[g] = W2 + (size_t)(nt * 128 + r) * 1536;
  }

  f32x4 acc[4][4];
#pragma unroll
  for (int mi = 0; mi < 4; ++mi)
#pragma unroll
    for (int ni = 0; ni < 4; ++ni) {
      acc[mi][ni][0] = 0.f; acc[mi][ni][1] = 0.f;
      acc[mi][ni][2] = 0.f; acc[mi][ni][3] = 0.f;
    }

  float4 pa[8];
  uint4 pb[4];
#pragma unroll
  for (int g = 0; g < 4; ++g) {
    int kp = gc8[g] * 8;
    int xc = kp & 511;
    pa[2 * g] = *(const float4*)(asrc[g] + xc);
    pa[2 * g + 1] = *(const float4*)(asrc[g] + xc + 4);
    pb[g] = *(const uint4*)(bsrc[g] + kp);
  }

  for (int it = 0; it < 24; ++it) {
    __syncthreads();
    {
      int k0 = it * 64;
#pragma unroll
      for (int g = 0; g < 4; ++g) {
        int kp = k0 + gc8[g] * 8;
        bool lofl = (kp >= 1024);
        const float* pf = (const float*)&pa[2 * g];
        s16x8 v;
#pragma unroll
        for (int j = 0; j < 8; ++j) {
          float f = pf[j];
          unsigned short hi = f2bf(f);
          v[j] = (short)(lofl ? f2bf(f - bf2f(hi)) : hi);
        }
        *(s16x8*)(&As[gr[g]][gc8[g] * 8]) = v;
        *(uint4*)(&Bs[gr[g]][gc8[g] * 8]) = pb[g];
      }
    }
    if (it + 1 < 24) {
      int k0 = (it + 1) * 64;
#pragma unroll
      for (int g = 0; g < 4; ++g) {
        int kp = k0 + gc8[g] * 8;
        int xc = kp & 511;
        pa[2 * g] = *(const float4*)(asrc[g] + xc);
        pa[2 * g + 1] = *(const float4*)(asrc[g] + xc + 4);
        pb[g] = *(const uint4*)(bsrc[g] + kp);
      }
    }
    __syncthreads();
#pragma unroll
    for (int kk = 0; kk < 64; kk += 32) {
      s16x8 af[4], bf[4];
#pragma unroll
      for (int mi = 0; mi < 4; ++mi)
        af[mi] = *(const s16x8*)(&As[wm * 64 + mi * 16 + lr][kk + lg * 8]);
#pragma unroll
      for (int ni = 0; ni < 4; ++ni)
        bf[ni] = *(const s16x8*)(&Bs[wn * 64 + ni * 16 + lr][kk + lg * 8]);
#pragma unroll
      for (int mi = 0; mi < 4; ++mi)
#pragma unroll
        for (int ni = 0; ni < 4; ++ni)
          acc[mi][ni] = __builtin_amdgcn_mfma_f32_16x16x32_bf16(
              af[mi], bf[ni], acc[mi][ni], 0, 0, 0);
    }
  }

  int g_ = (nt * 128) >> 10;
  const float* bias = (g_ == 0) ? bz : ((g_ == 1) ? br : bh);
#pragma unroll
  for (int ni = 0; ni < 4; ++ni) {
    int col = nt * 128 + wn * 64 + ni * 16 + lr;
    int jc = col & 1023;
    float bv = bias[jc];
#pragma unroll
    for (int mi = 0; mi < 4; ++mi) {
      int nrow = mt * 128 + wm * 64 + mi * 16 + lg * 4;
      int b = nrow / Tc, tt = nrow % Tc;
#pragma unroll
      for (int v = 0; v < 4; ++v) {
        XP[((size_t)((tt * 3 + g_) * 64 + b)) * 1024 + jc] = acc[mi][ni][v] + bv;
        if (++tt == Tc) { tt = 0; ++b; }
      }
    }
  }
}

// ---- persistent recurrence kernel ----
// wgs 0..63: phase A z-cols; 64..127: phase A r-cols (produce s2);
// 128..191: phase B h~-cols (h slice in storer registers).
// Epilogues: 128 storer lanes/wg, 8 consecutive cols each, dwordx4 sc-stores.
__global__ __launch_bounds__(512) void k_recur(
    const float* __restrict__ Uz, const float* __restrict__ Ur,
    const float* __restrict__ Uh, const float* __restrict__ XP,
    int t0i, int Tcc, float* __restrict__ h, uint16_t* __restrict__ h2,
    uint16_t* __restrict__ s2, float* __restrict__ zbuf,
    float* __restrict__ out, unsigned* __restrict__ flagsA,
    unsigned* __restrict__ flagsB) {
  __shared__ uint16_t Wl[16 * 2048];       // [hi|lo] per U-row
  __shared__ float red[8 * 64 * 17];
  __shared__ float sums[64 * 17];

  const int tid = threadIdx.x;
  const int w = tid >> 6, l = tid & 63;
  const int lr = l & 15, lg = l >> 4;
  const int bid = blockIdx.x;
  const bool isA = (bid < NWG_A);
  const int tile = isA ? bid : (bid - NWG_A);
  const int n0 = tile * 16;
  const bool isR = isA && (n0 >= 1024);

  // stage weights fp32 -> [hi|lo] bf16, XOR-swizzled rows (once)
  const float* src = isA ? ((n0 < 1024) ? (Uz + (size_t)n0 * 1024)
                                        : (Ur + (size_t)(n0 - 1024) * 1024))
                         : (Uh + (size_t)n0 * 1024);
  for (int i = tid; i < 2048; i += 512) {
    int r = i >> 7;
    int k8 = (i & 127) * 8;
    const float* p = src + r * 1024 + k8;
    s16x8 hi8, lo8;
#pragma unroll
    for (int j = 0; j < 8; ++j) {
      float f = p[j];
      unsigned short hb = f2bf(f);
      hi8[j] = (short)hb;
      lo8[j] = (short)f2bf(f - bf2f(hb));
    }
    uint8_t* rowp = (uint8_t*)Wl + r * 4096;
    int swz = (r & 7) << 4;
    *(s16x8*)(rowp + ((k8 * 2) ^ swz)) = hi8;
    *(s16x8*)(rowp + (((1024 + k8) * 2) ^ swz)) = lo8;
  }
  __syncthreads();

  const int KB0 = w * 128;
  const int bswz = (lr & 7) << 4;
  const uint8_t* browp = (const uint8_t*)Wl + lr * 4096;

  int eb[2], ec[2];
#pragma unroll
  for (int u = 0; u < 2; ++u) {
    int e = tid + u * 512;
    eb[u] = e >> 4; ec[u] = e & 15;
  }

  // storer role: 128 lanes own 8 consecutive cols each
  const bool isStorer = ((tid & 3) == 0);
  const int sidx = tid >> 2;            // 0..127
  const int sb = sidx >> 1, sc8 = (sidx & 1) * 8;

  // B-wgs: h slice lives in storer registers across the whole chunk
  float hreg8[8] = {0.f, 0.f, 0.f, 0.f, 0.f, 0.f, 0.f, 0.f};
  if (!isA && isStorer) {
    const float* hp = h + sb * 1024 + n0 + sc8;
#pragma unroll
    for (int q = 0; q < 8; ++q) hreg8[q] = hp[q];
  }

  for (int tt = 0; tt < Tcc; ++tt) {
    const int t = t0i + tt;

    // XP prefetch (plain cached; XP immutable during this launch)
    float xpre[2];
    {
      int gate = isA ? (isR ? 1 : 0) : 2;
#pragma unroll
      for (int u = 0; u < 2; ++u) {
        int jc = (n0 + ec[u]) & 1023;
        xpre[u] = XP[((size_t)(tt * 3 + gate) * 64 + eb[u]) * 1024 + jc];
      }
    }

    if (isA) {
      // wait for phase B of step t-1
      if (t > 0 && w == 0) {
        const unsigned* fp = flagsB + (size_t)l * FSTR;
        for (;;) {
          unsigned f;
          asm volatile("global_load_dword %0, %1, off sc0 sc1\n\t"
                       "s_waitcnt vmcnt(0)"
                       : "=v"(f) : "v"(fp) : "memory");
          if (__all(f >= (unsigned)t)) break;
          __builtin_amdgcn_s_sleep(4);
        }
        if (l == 0)
          (void)__hip_atomic_load(flagsB, __ATOMIC_ACQUIRE,
                                  __HIP_MEMORY_SCOPE_AGENT);  // buffer_inv
        vm_drain();
      }
      __syncthreads();

      s16x8 ah[4][4], al[4][4];
#pragma unroll
      for (int ks = 0; ks < 4; ++ks)
#pragma unroll
        for (int mi = 0; mi < 4; ++mi)
          ah[ks][mi] = sc0_load_b128(h2 + (size_t)(lr + 16 * mi) * 2048 +
                                     (KB0 + ks * 32 + lg * 8));
#pragma unroll
      for (int ks = 0; ks < 4; ++ks)
#pragma unroll
        for (int mi = 0; mi < 4; ++mi)
          al[ks][mi] = sc0_load_b128(h2 + (size_t)(lr + 16 * mi) * 2048 +
                                     (1024 + KB0 + ks * 32 + lg * 8));

      f32x4 acc[4];
#pragma unroll
      for (int mi = 0; mi < 4; ++mi) {
        acc[mi][0] = 0.f; acc[mi][1] = 0.f; acc[mi][2] = 0.f; acc[mi][3] = 0.f;
      }

      asm volatile("s_waitcnt vmcnt(16)" ::: "memory");
      __builtin_amdgcn_sched_barrier(0);
      s16x8 bfv0[4];
#pragma unroll
      for (int ks = 0; ks < 4; ++ks) {   // seg0: A_hi * B_hi
        int kp = KB0 + ks * 32 + lg * 8;
        bfv0[ks] = *(const s16x8*)(browp + ((kp * 2) ^ bswz));
#pragma unroll
        for (int mi = 0; mi < 4; ++mi)
          acc[mi] = __builtin_amdgcn_mfma_f32_16x16x32_bf16(ah[ks][mi], bfv0[ks],
                                                            acc[mi], 0, 0, 0);
      }
#pragma unroll
      for (int ks = 0; ks < 4; ++ks) {   // seg1: A_hi * B_lo
        int kp = KB0 + ks * 32 + lg * 8;
        s16x8 bfv = *(const s16x8*)(browp + (((1024 + kp) * 2) ^ bswz));
#pragma unroll
        for (int mi = 0; mi < 4; ++mi)
          acc[mi] = __builtin_amdgcn_mfma_f32_16x16x32_bf16(ah[ks][mi], bfv,
                                                            acc[mi], 0, 0, 0);
      }
      vm_drain();
      __builtin_amdgcn_sched_barrier(0);
#pragma unroll
      for (int ks = 0; ks < 4; ++ks)     // seg2: A_lo * B_hi (reg reuse)
#pragma unroll
        for (int mi = 0; mi < 4; ++mi)
          acc[mi] = __builtin_amdgcn_mfma_f32_16x16x32_bf16(al[ks][mi], bfv0[ks],
                                                            acc[mi], 0, 0, 0);
#pragma unroll
      for (int mi = 0; mi < 4; ++mi)
#pragma unroll
        for (int v = 0; v < 4; ++v)
          red[(w * 64 + mi * 16 + lg * 4 + v) * 17 + lr] = acc[mi][v];
      __syncthreads();

#pragma unroll
      for (int u = 0; u < 2; ++u) {
        int b = eb[u], c = ec[u];
        float s = 0.f;
#pragma unroll
        for (int q = 0; q < 8; ++q) s += red[(q * 64 + b) * 17 + c];
        sums[b * 17 + c] = s + xpre[u];
      }
      __syncthreads();

      if (isStorer) {
        if (!isR) {
          f32x4 z0, z1;
#pragma unroll
          for (int q = 0; q < 8; ++q) {
            float pre = sums[sb * 17 + sc8 + q];
            float zq = 1.f / (1.f + __expf(-pre));
            if (q < 4) z0[q] = zq; else z1[q - 4] = zq;
          }
          sc_store_f32x4(zbuf + sb * 1024 + n0 + sc8, z0);
          sc_store_f32x4(zbuf + sb * 1024 + n0 + sc8 + 4, z1);
        } else {
          int j = n0 - 1024 + sc8;
          s16x8 hh = sc0_load_b128(h2 + sb * 2048 + j);
          s16x8 hl = sc0_load_b128(h2 + sb * 2048 + 1024 + j);
          vm_drain();
          s16x8 shi, slo;
#pragma unroll
          for (int q = 0; q < 8; ++q) {
            float pre = sums[sb * 17 + sc8 + q];
            float r = 1.f / (1.f + __expf(-pre));
            float hv = bf2f((unsigned short)hh[q]) + bf2f((unsigned short)hl[q]);
            float sv = r * hv;
            unsigned short hb = f2bf(sv);
            shi[q] = (short)hb;
            slo[q] = (short)f2bf(sv - bf2f(hb));
          }
          sc_store_b128(s2 + sb * 2048 + j, shi);
          sc_store_b128(s2 + sb * 2048 + 1024 + j, slo);
        }
      }
      vm_drain();
      __syncthreads();
      if (tid == 0) sc_store_u32(flagsA + (size_t)tile * FSTR, (unsigned)(t + 1));
    } else {
      // ---- phase B ----
      if (w == 0) {
        const unsigned* fp0 = flagsA + (size_t)(2 * l) * FSTR;
        const unsigned* fp1 = flagsA + (size_t)(2 * l + 1) * FSTR;
        unsigned tgt = (unsigned)(t + 1);
        for (;;) {
          unsigned f0, f1;
          asm volatile("global_load_dword %0, %2, off sc0 sc1\n\t"
                       "global_load_dword %1, %3, off sc0 sc1\n\t"
                       "s_waitcnt vmcnt(0)"
                       : "=v"(f0), "=v"(f1) : "v"(fp0), "v"(fp1) : "memory");
          if (__all((f0 >= tgt) && (f1 >= tgt))) break;
          __builtin_amdgcn_s_sleep(4);
        }
        if (l == 0)
          (void)__hip_atomic_load(flagsA, __ATOMIC_ACQUIRE,
                                  __HIP_MEMORY_SCOPE_AGENT);  // buffer_inv
        vm_drain();
      }
      __syncthreads();

      // early z loads (L2/IC; used only in epilogue)
      f32x4 zp0, zp1;
      if (isStorer) {
        zp0 = sc0_load_f32x4(zbuf + sb * 1024 + n0 + sc8);
        zp1 = sc0_load_f32x4(zbuf + sb * 1024 + n0 + sc8 + 4);
      }

      s16x8 ah[4][4], al[4][4];
#pragma unroll
      for (int ks = 0; ks < 4; ++ks)
#pragma unroll
        for (int mi = 0; mi < 4; ++mi)
          ah[ks][mi] = sc0_load_b128(s2 + (size_t)(lr + 16 * mi) * 2048 +
                                     (KB0 + ks * 32 + lg * 8));
#pragma unroll
      for (int ks = 0; ks < 4; ++ks)
#pragma unroll
        for (int mi = 0; mi < 4; ++mi)
          al[ks][mi] = sc0_load_b128(s2 + (size_t)(lr + 16 * mi) * 2048 +
                                     (1024 + KB0 + ks * 32 + lg * 8));

      f32x4 acc[4];
#pragma unroll
      for (int mi = 0; mi < 4; ++mi) {
        acc[mi][0] = 0.f; acc[mi][1] = 0.f; acc[mi][2] = 0.f; acc[mi][3] = 0.f;
      }

      // completed >= (zp 2) + ah(16) when <=18 outstanding
      asm volatile("s_waitcnt vmcnt(18)" ::: "memory");
      __builtin_amdgcn_sched_barrier(0);
      s16x8 bfv0[4];
#pragma unroll
      for (int ks = 0; ks < 4; ++ks) {
        int kp = KB0 + ks * 32 + lg * 8;
        bfv0[ks] = *(const s16x8*)(browp + ((kp * 2) ^ bswz));
#pragma unroll
        for (int mi = 0; mi < 4; ++mi)
          acc[mi] = __builtin_amdgcn_mfma_f32_16x16x32_bf16(ah[ks][mi], bfv0[ks],
                                                            acc[mi], 0, 0, 0);
      }
#pragma unroll
      for (int ks = 0; ks < 4; ++ks) {
        int kp = KB0 + ks * 32 + lg * 8;
        s16x8 bfv = *(const s16x8*)(browp + (((1024 + kp) * 2) ^ bswz));
#pragma unroll
        for (int mi = 0; mi < 4; ++mi)
          acc[mi] = __builtin_amdgcn_mfma_f32_16x16x32_bf16(ah[ks][mi], bfv,
                                                            acc[mi], 0, 0, 0);
      }
      vm_drain();
      __builtin_amdgcn_sched_barrier(0);
#pragma unroll
      for (int ks = 0; ks < 4; ++ks)
#pragma unroll
        for (int mi = 0; mi < 4; ++mi)
          acc[mi] = __builtin_amdgcn_mfma_f32_16x16x32_bf16(al[ks][mi], bfv0[ks],
                                                            acc[mi], 0, 0, 0);
#pragma unroll
      for (int mi = 0; mi < 4; ++mi)
#pragma unroll
        for (int v = 0; v < 4; ++v)
          red[(w * 64 + mi * 16 + lg * 4 + v) * 17 + lr] = acc[mi][v];
      __syncthreads();

#pragma unroll
      for (int u = 0; u < 2; ++u) {
        int b = eb[u], c = ec[u];
        float s = 0.f;
#pragma unroll
        for (int q = 0; q < 8; ++q) s += red[(q * 64 + b) * 17 + c];
        sums[b * 17 + c] = s + xpre[u];
      }
      __syncthreads();

      if (isStorer) {
        int j = n0 + sc8;
        s16x8 hhi, hlo;
        f32x4 o0, o1;
#pragma unroll
        for (int q = 0; q < 8; ++q) {
          float pre = sums[sb * 17 + sc8 + q];
          float ht = tanhf(pre);
          float z = (q < 4) ? zp0[q] : zp1[q - 4];
          float hn = (1.f - z) * hreg8[q] + z * ht;
          hreg8[q] = hn;
          unsigned short hb = f2bf(hn);
          hhi[q] = (short)hb;
          hlo[q] = (short)f2bf(hn - bf2f(hb));
          if (q < 4) o0[q] = hn; else o1[q - 4] = hn;
        }
        sc_store_b128(h2 + sb * 2048 + j, hhi);
        sc_store_b128(h2 + sb * 2048 + 1024 + j, hlo);
        *(f32x4*)(out + ((size_t)sb * T_ + t) * 1024 + j) = o0;
        *(f32x4*)(out + ((size_t)sb * T_ + t) * 1024 + j + 4) = o1;
        if (t == T_ - 1) {
          *(f32x4*)(out + (size_t)B_ * T_ * 1024 + sb * 1024 + j) = o0;
          *(f32x4*)(out + (size_t)B_ * T_ * 1024 + sb * 1024 + j + 4) = o1;
        }
        if (tt == Tcc - 1) {
          *(f32x4*)(h + sb * 1024 + j) = o0;
          *(f32x4*)(h + sb * 1024 + j + 4) = o1;
        }
      }
      vm_drain();
      __syncthreads();
      if (tid == 0) sc_store_u32(flagsB + (size_t)tile * FSTR, (unsigned)(t + 1));
    }
  }
}

extern "C" void kernel_launch(void* const* d_in, const int* in_sizes, int n_in,
                              void* d_out, int out_size, void* d_ws, size_t ws_size,
                              hipStream_t stream) {
  const float* x  = (const float*)d_in[0];
  const float* h0 = (const float*)d_in[1];
  const float* Wz = (const float*)d_in[2];
  const float* bz = (const float*)d_in[3];
  const float* Uz = (const float*)d_in[4];
  const float* Wr = (const float*)d_in[5];
  const float* br = (const float*)d_in[6];
  const float* Ur = (const float*)d_in[7];
  const float* Wh = (const float*)d_in[8];
  const float* bh = (const float*)d_in[9];
  const float* Uh = (const float*)d_in[10];
  float* out = (float*)d_out;

  uint8_t* ws = (uint8_t*)d_ws;
  uint16_t* W2    = (uint16_t*)(ws + 0);          // [3072][1536] bf16
  float*    hbuf  = (float*)   (ws + 9437184);    // [64][1024]
  uint16_t* h2    = (uint16_t*)(ws + 9699328);    // [64][2048]
  uint16_t* s2    = (uint16_t*)(ws + 9961472);    // [64][2048]
  float*    zbuf  = (float*)   (ws + 10223616);   // [64][1024]
  unsigned* flagsA= (unsigned*)(ws + 10485760);   // 128 x 256B
  unsigned* flagsB= (unsigned*)(ws + 10518528);   // 64 x 256B
  float*    XP    = (float*)   (ws + 10534912);   // [Tc][3][64][1024] fp32

  hipMemsetAsync((void*)flagsA, 0, 49152, stream);

  k_split<<<512, 256, 0, stream>>>(Wz, W2, 9, 1024 * 512);
  k_split<<<512, 256, 0, stream>>>(Wr, W2 + (size_t)1024 * 1536, 9, 1024 * 512);
  k_split<<<512, 256, 0, stream>>>(Wh, W2 + (size_t)2048 * 1536, 9, 1024 * 512);
  k_init<<<64, 256, 0, stream>>>(h0, hbuf, h2);

  size_t avail = (ws_size > 10534912u) ? (ws_size - 10534912u) : 0u;
  long long tcl = (long long)(avail / 786432u);
  int Tc = (tcl > 512) ? 512 : (int)tcl;
  Tc &= ~1;
  if (Tc < 2) Tc = 2;

  for (int t0 = 0; t0 < T_; t0 += Tc) {
    int Tcc = (Tc < T_ - t0) ? Tc : (T_ - t0);
    int MT = (B_ * Tcc) / 128;
    k_proj<<<MT * 24, 256, 0, stream>>>(x, W2, bz, br, bh, XP, t0, Tcc, MT);

    int t0v = t0, tccv = Tcc;
    void* args[] = {(void*)&Uz, (void*)&Ur, (void*)&Uh, (void*)&XP,
                    (void*)&t0v, (void*)&tccv, (void*)&hbuf, (void*)&h2,
                    (void*)&s2, (void*)&zbuf, (void*)&out,
                    (void*)&flagsA, (void*)&flagsB};
    hipLaunchCooperativeKernel((void*)k_recur, dim3(NWG), dim3(512),
                               args, 0, stream);
  }
}

// Round 6
// 17527.843 us; speedup vs baseline: 1.3575x; 1.3575x over previous
//
#include <hip/hip_runtime.h>
#include <hip/hip_bf16.h>
#include <stdint.h>

// GRU B=64 T=512 I=512 H=1024, fp32 in/out.
// bf16 hi/lo 3-pass MFMA numerics.
// Round 6: flag-fabric collapse. 8 aggregate counters per phase (atomic add,
// 1 per producer wg), consumers poll with 8 lanes of wave0 only + s_sleep
// backoff. Tests the poll fan-in contention theory for the ~15us/phase floor.

#define B_ 64
#define T_ 512
#define I_ 512
#define H_ 1024
#define NWG_A 128
#define NWG_B 64
#define NWG 192
#define FSTR 64   // counter padding stride (uints) = 256B

typedef __attribute__((ext_vector_type(4))) float f32x4;
typedef __attribute__((ext_vector_type(8))) short s16x8;

__device__ __forceinline__ unsigned short f2bf(float f) {
  union { float f; uint32_t u; } v; v.f = f;
  uint32_t u = v.u;
  u += 0x7fffu + ((u >> 16) & 1u);   // RNE
  return (unsigned short)(u >> 16);
}
__device__ __forceinline__ float bf2f(unsigned short h) {
  union { uint32_t u; float f; } v; v.u = ((uint32_t)h) << 16;
  return v.f;
}

// ---- coherent write-through stores (visible at coherence point) ----
__device__ __forceinline__ void sc_store_b128(uint16_t* p, s16x8 v) {
  asm volatile("global_store_dwordx4 %0, %1, off sc0 sc1"
               :: "v"(p), "v"(v) : "memory");
}
__device__ __forceinline__ void sc_store_f32x4(float* p, f32x4 v) {
  asm volatile("global_store_dwordx4 %0, %1, off sc0 sc1"
               :: "v"(p), "v"(v) : "memory");
}
// ---- L2-cached consumer loads (fresh after agent-acquire buffer_inv) ----
__device__ __forceinline__ s16x8 sc0_load_b128(const uint16_t* p) {
  s16x8 r;
  asm volatile("global_load_dwordx4 %0, %1, off sc0"
               : "=v"(r) : "v"(p) : "memory");
  return r;
}
__device__ __forceinline__ f32x4 sc0_load_f32x4(const float* p) {
  f32x4 r;
  asm volatile("global_load_dwordx4 %0, %1, off sc0"
               : "=v"(r) : "v"(p) : "memory");
  return r;
}
__device__ __forceinline__ void vm_drain() {
  asm volatile("s_waitcnt vmcnt(0)" ::: "memory");
}

// src [N][K] fp32 -> dst [N][3K] bf16 as [hi | lo | hi] K-blocks. K = 1<<kshift.
__global__ void k_split(const float* __restrict__ src, uint16_t* __restrict__ dst,
                        int kshift, int total) {
  int K = 1 << kshift;
  for (int i = blockIdx.x * blockDim.x + threadIdx.x; i < total;
       i += gridDim.x * blockDim.x) {
    int n = i >> kshift, k = i & (K - 1);
    float f = src[i];
    unsigned short hi = f2bf(f);
    unsigned short lo = f2bf(f - bf2f(hi));
    size_t base = (size_t)n * (3 * K);
    dst[base + k] = hi;
    dst[base + K + k] = lo;
    dst[base + 2 * K + k] = hi;
  }
}

__global__ void k_init(const float* __restrict__ h0, float* __restrict__ h,
                       uint16_t* __restrict__ h2) {
  for (int i = blockIdx.x * blockDim.x + threadIdx.x; i < B_ * H_;
       i += gridDim.x * blockDim.x) {
    float f = h0[i];
    h[i] = f;
    int b = i >> 10, j = i & 1023;
    unsigned short hi = f2bf(f);
    h2[b * 2048 + j] = hi;
    h2[b * 2048 + 1024 + j] = f2bf(f - bf2f(hi));
  }
}

// Projection GEMM (unchanged): XP[tt][gate][b][j] = x@W^T + bias
__global__ __launch_bounds__(256) void k_proj(
    const float* __restrict__ x, const uint16_t* __restrict__ W2,
    const float* __restrict__ bz, const float* __restrict__ br,
    const float* __restrict__ bh,
    float* __restrict__ XP, int t0, int Tc, int MT) {
  __shared__ uint16_t As[128][72];
  __shared__ uint16_t Bs[128][72];
  int bid = blockIdx.x;
  int mt = bid % MT, nt = bid / MT;
  int tid = threadIdx.x;
  int w = tid >> 6, l = tid & 63;
  int wm = w >> 1, wn = w & 1;
  int lr = l & 15, lg = l >> 4;

  int gr[4], gc8[4];
  const float* asrc[4];
  const uint16_t* bsrc[4];
#pragma unroll
  for (int g = 0; g < 4; ++g) {
    int gran = tid + 256 * g;
    int r = gran >> 3, c8 = gran & 7;
    gr[g] = r; gc8[g] = c8;
    int n = mt * 128 + r;
    int b = n / Tc, tt = n % Tc;
    asrc[g] = x + ((size_t)b * T_ + (t0 + tt)) * I_;
    bsrc[g] = W2 + (size_t)(nt * 128 + r) * 1536;
  }

  f32x4 acc[4][4];
#pragma unroll
  for (int mi = 0; mi < 4; ++mi)
#pragma unroll
    for (int ni = 0; ni < 4; ++ni) {
      acc[mi][ni][0] = 0.f; acc[mi][ni][1] = 0.f;
      acc[mi][ni][2] = 0.f; acc[mi][ni][3] = 0.f;
    }

  float4 pa[8];
  uint4 pb[4];
#pragma unroll
  for (int g = 0; g < 4; ++g) {
    int kp = gc8[g] * 8;
    int xc = kp & 511;
    pa[2 * g] = *(const float4*)(asrc[g] + xc);
    pa[2 * g + 1] = *(const float4*)(asrc[g] + xc + 4);
    pb[g] = *(const uint4*)(bsrc[g] + kp);
  }

  for (int it = 0; it < 24; ++it) {
    __syncthreads();
    {
      int k0 = it * 64;
#pragma unroll
      for (int g = 0; g < 4; ++g) {
        int kp = k0 + gc8[g] * 8;
        bool lofl = (kp >= 1024);
        const float* pf = (const float*)&pa[2 * g];
        s16x8 v;
#pragma unroll
        for (int j = 0; j < 8; ++j) {
          float f = pf[j];
          unsigned short hi = f2bf(f);
          v[j] = (short)(lofl ? f2bf(f - bf2f(hi)) : hi);
        }
        *(s16x8*)(&As[gr[g]][gc8[g] * 8]) = v;
        *(uint4*)(&Bs[gr[g]][gc8[g] * 8]) = pb[g];
      }
    }
    if (it + 1 < 24) {
      int k0 = (it + 1) * 64;
#pragma unroll
      for (int g = 0; g < 4; ++g) {
        int kp = k0 + gc8[g] * 8;
        int xc = kp & 511;
        pa[2 * g] = *(const float4*)(asrc[g] + xc);
        pa[2 * g + 1] = *(const float4*)(asrc[g] + xc + 4);
        pb[g] = *(const uint4*)(bsrc[g] + kp);
      }
    }
    __syncthreads();
#pragma unroll
    for (int kk = 0; kk < 64; kk += 32) {
      s16x8 af[4], bf[4];
#pragma unroll
      for (int mi = 0; mi < 4; ++mi)
        af[mi] = *(const s16x8*)(&As[wm * 64 + mi * 16 + lr][kk + lg * 8]);
#pragma unroll
      for (int ni = 0; ni < 4; ++ni)
        bf[ni] = *(const s16x8*)(&Bs[wn * 64 + ni * 16 + lr][kk + lg * 8]);
#pragma unroll
      for (int mi = 0; mi < 4; ++mi)
#pragma unroll
        for (int ni = 0; ni < 4; ++ni)
          acc[mi][ni] = __builtin_amdgcn_mfma_f32_16x16x32_bf16(
              af[mi], bf[ni], acc[mi][ni], 0, 0, 0);
    }
  }

  int g_ = (nt * 128) >> 10;
  const float* bias = (g_ == 0) ? bz : ((g_ == 1) ? br : bh);
#pragma unroll
  for (int ni = 0; ni < 4; ++ni) {
    int col = nt * 128 + wn * 64 + ni * 16 + lr;
    int jc = col & 1023;
    float bv = bias[jc];
#pragma unroll
    for (int mi = 0; mi < 4; ++mi) {
      int nrow = mt * 128 + wm * 64 + mi * 16 + lg * 4;
      int b = nrow / Tc, tt = nrow % Tc;
#pragma unroll
      for (int v = 0; v < 4; ++v) {
        XP[((size_t)((tt * 3 + g_) * 64 + b)) * 1024 + jc] = acc[mi][ni][v] + bv;
        if (++tt == Tc) { tt = 0; ++b; }
      }
    }
  }
}

// ---- persistent recurrence kernel ----
// wgs 0..63: phase A z-cols; 64..127: phase A r-cols (produce s2);
// 128..191: phase B h~-cols (h slice in storer registers).
// Sync: cntA[8]/cntB[8] aggregate counters (256B stride). Producer: one
// relaxed agent atomic-add per wg. Consumer: 8 lanes of wave0 poll.
__global__ __launch_bounds__(512) void k_recur(
    const float* __restrict__ Uz, const float* __restrict__ Ur,
    const float* __restrict__ Uh, const float* __restrict__ XP,
    int t0i, int Tcc, float* __restrict__ h, uint16_t* __restrict__ h2,
    uint16_t* __restrict__ s2, float* __restrict__ zbuf,
    float* __restrict__ out, unsigned* __restrict__ cntA,
    unsigned* __restrict__ cntB) {
  __shared__ uint16_t Wl[16 * 2048];       // [hi|lo] per U-row
  __shared__ float red[8 * 64 * 17];
  __shared__ float sums[64 * 17];

  const int tid = threadIdx.x;
  const int w = tid >> 6, l = tid & 63;
  const int lr = l & 15, lg = l >> 4;
  const int bid = blockIdx.x;
  const bool isA = (bid < NWG_A);
  const int tile = isA ? bid : (bid - NWG_A);
  const int n0 = tile * 16;
  const bool isR = isA && (n0 >= 1024);

  // stage weights fp32 -> [hi|lo] bf16, XOR-swizzled rows (once)
  const float* src = isA ? ((n0 < 1024) ? (Uz + (size_t)n0 * 1024)
                                        : (Ur + (size_t)(n0 - 1024) * 1024))
                         : (Uh + (size_t)n0 * 1024);
  for (int i = tid; i < 2048; i += 512) {
    int r = i >> 7;
    int k8 = (i & 127) * 8;
    const float* p = src + r * 1024 + k8;
    s16x8 hi8, lo8;
#pragma unroll
    for (int j = 0; j < 8; ++j) {
      float f = p[j];
      unsigned short hb = f2bf(f);
      hi8[j] = (short)hb;
      lo8[j] = (short)f2bf(f - bf2f(hb));
    }
    uint8_t* rowp = (uint8_t*)Wl + r * 4096;
    int swz = (r & 7) << 4;
    *(s16x8*)(rowp + ((k8 * 2) ^ swz)) = hi8;
    *(s16x8*)(rowp + (((1024 + k8) * 2) ^ swz)) = lo8;
  }
  __syncthreads();

  const int KB0 = w * 128;
  const int bswz = (lr & 7) << 4;
  const uint8_t* browp = (const uint8_t*)Wl + lr * 4096;

  int eb[2], ec[2];
#pragma unroll
  for (int u = 0; u < 2; ++u) {
    int e = tid + u * 512;
    eb[u] = e >> 4; ec[u] = e & 15;
  }

  // storer role: 128 lanes own 8 consecutive cols each
  const bool isStorer = ((tid & 3) == 0);
  const int sidx = tid >> 2;            // 0..127
  const int sb = sidx >> 1, sc8 = (sidx & 1) * 8;

  // B-wgs: h slice lives in storer registers across the whole chunk
  float hreg8[8] = {0.f, 0.f, 0.f, 0.f, 0.f, 0.f, 0.f, 0.f};
  if (!isA && isStorer) {
    const float* hp = h + sb * 1024 + n0 + sc8;
#pragma unroll
    for (int q = 0; q < 8; ++q) hreg8[q] = hp[q];
  }

  for (int tt = 0; tt < Tcc; ++tt) {
    const int t = t0i + tt;

    // XP prefetch (plain cached; XP immutable during this launch)
    float xpre[2];
    {
      int gate = isA ? (isR ? 1 : 0) : 2;
#pragma unroll
      for (int u = 0; u < 2; ++u) {
        int jc = (n0 + ec[u]) & 1023;
        xpre[u] = XP[((size_t)(tt * 3 + gate) * 64 + eb[u]) * 1024 + jc];
      }
    }

    if (isA) {
      // wait for phase B of step t-1 (cntB reaches t*8 on each of 8 lines)
      if (t > 0 && w == 0) {
        const unsigned* cp = cntB + (size_t)(l & 7) * FSTR;
        unsigned tgt = (unsigned)t * 8u;
        for (;;) {
          unsigned f = 0xffffffffu;
          if (l < 8) {
            asm volatile("global_load_dword %0, %1, off sc0 sc1\n\t"
                         "s_waitcnt vmcnt(0)"
                         : "=v"(f) : "v"(cp) : "memory");
          }
          if (__all(f >= tgt)) break;
          __builtin_amdgcn_s_sleep(8);
        }
        if (l == 0)
          (void)__hip_atomic_load(cntB, __ATOMIC_ACQUIRE,
                                  __HIP_MEMORY_SCOPE_AGENT);  // buffer_inv
        vm_drain();
      }
      __syncthreads();

      s16x8 ah[4][4], al[4][4];
#pragma unroll
      for (int ks = 0; ks < 4; ++ks)
#pragma unroll
        for (int mi = 0; mi < 4; ++mi)
          ah[ks][mi] = sc0_load_b128(h2 + (size_t)(lr + 16 * mi) * 2048 +
                                     (KB0 + ks * 32 + lg * 8));
#pragma unroll
      for (int ks = 0; ks < 4; ++ks)
#pragma unroll
        for (int mi = 0; mi < 4; ++mi)
          al[ks][mi] = sc0_load_b128(h2 + (size_t)(lr + 16 * mi) * 2048 +
                                     (1024 + KB0 + ks * 32 + lg * 8));

      f32x4 acc[4];
#pragma unroll
      for (int mi = 0; mi < 4; ++mi) {
        acc[mi][0] = 0.f; acc[mi][1] = 0.f; acc[mi][2] = 0.f; acc[mi][3] = 0.f;
      }

      asm volatile("s_waitcnt vmcnt(16)" ::: "memory");
      __builtin_amdgcn_sched_barrier(0);
      s16x8 bfv0[4];
#pragma unroll
      for (int ks = 0; ks < 4; ++ks) {   // seg0: A_hi * B_hi
        int kp = KB0 + ks * 32 + lg * 8;
        bfv0[ks] = *(const s16x8*)(browp + ((kp * 2) ^ bswz));
#pragma unroll
        for (int mi = 0; mi < 4; ++mi)
          acc[mi] = __builtin_amdgcn_mfma_f32_16x16x32_bf16(ah[ks][mi], bfv0[ks],
                                                            acc[mi], 0, 0, 0);
      }
#pragma unroll
      for (int ks = 0; ks < 4; ++ks) {   // seg1: A_hi * B_lo
        int kp = KB0 + ks * 32 + lg * 8;
        s16x8 bfv = *(const s16x8*)(browp + (((1024 + kp) * 2) ^ bswz));
#pragma unroll
        for (int mi = 0; mi < 4; ++mi)
          acc[mi] = __builtin_amdgcn_mfma_f32_16x16x32_bf16(ah[ks][mi], bfv,
                                                            acc[mi], 0, 0, 0);
      }
      vm_drain();
      __builtin_amdgcn_sched_barrier(0);
#pragma unroll
      for (int ks = 0; ks < 4; ++ks)     // seg2: A_lo * B_hi (reg reuse)
#pragma unroll
        for (int mi = 0; mi < 4; ++mi)
          acc[mi] = __builtin_amdgcn_mfma_f32_16x16x32_bf16(al[ks][mi], bfv0[ks],
                                                            acc[mi], 0, 0, 0);
#pragma unroll
      for (int mi = 0; mi < 4; ++mi)
#pragma unroll
        for (int v = 0; v < 4; ++v)
          red[(w * 64 + mi * 16 + lg * 4 + v) * 17 + lr] = acc[mi][v];
      __syncthreads();

#pragma unroll
      for (int u = 0; u < 2; ++u) {
        int b = eb[u], c = ec[u];
        float s = 0.f;
#pragma unroll
        for (int q = 0; q < 8; ++q) s += red[(q * 64 + b) * 17 + c];
        sums[b * 17 + c] = s + xpre[u];
      }
      __syncthreads();

      if (isStorer) {
        if (!isR) {
          f32x4 z0, z1;
#pragma unroll
          for (int q = 0; q < 8; ++q) {
            float pre = sums[sb * 17 + sc8 + q];
            float zq = 1.f / (1.f + __expf(-pre));
            if (q < 4) z0[q] = zq; else z1[q - 4] = zq;
          }
          sc_store_f32x4(zbuf + sb * 1024 + n0 + sc8, z0);
          sc_store_f32x4(zbuf + sb * 1024 + n0 + sc8 + 4, z1);
        } else {
          int j = n0 - 1024 + sc8;
          s16x8 hh = sc0_load_b128(h2 + sb * 2048 + j);
          s16x8 hl = sc0_load_b128(h2 + sb * 2048 + 1024 + j);
          vm_drain();
          s16x8 shi, slo;
#pragma unroll
          for (int q = 0; q < 8; ++q) {
            float pre = sums[sb * 17 + sc8 + q];
            float r = 1.f / (1.f + __expf(-pre));
            float hv = bf2f((unsigned short)hh[q]) + bf2f((unsigned short)hl[q]);
            float sv = r * hv;
            unsigned short hb = f2bf(sv);
            shi[q] = (short)hb;
            slo[q] = (short)f2bf(sv - bf2f(hb));
          }
          sc_store_b128(s2 + sb * 2048 + j, shi);
          sc_store_b128(s2 + sb * 2048 + 1024 + j, slo);
        }
      }
      vm_drain();
      __syncthreads();
      if (tid == 0)
        __hip_atomic_fetch_add(cntA + (size_t)(bid & 7) * FSTR, 1u,
                               __ATOMIC_RELAXED, __HIP_MEMORY_SCOPE_AGENT);
    } else {
      // ---- phase B ----  wait for all 128 A wgs: cntA reaches (t+1)*16
      if (w == 0) {
        const unsigned* cp = cntA + (size_t)(l & 7) * FSTR;
        unsigned tgt = (unsigned)(t + 1) * 16u;
        for (;;) {
          unsigned f = 0xffffffffu;
          if (l < 8) {
            asm volatile("global_load_dword %0, %1, off sc0 sc1\n\t"
                         "s_waitcnt vmcnt(0)"
                         : "=v"(f) : "v"(cp) : "memory");
          }
          if (__all(f >= tgt)) break;
          __builtin_amdgcn_s_sleep(8);
        }
        if (l == 0)
          (void)__hip_atomic_load(cntA, __ATOMIC_ACQUIRE,
                                  __HIP_MEMORY_SCOPE_AGENT);  // buffer_inv
        vm_drain();
      }
      __syncthreads();

      // early z loads (L2; used only in epilogue)
      f32x4 zp0, zp1;
      if (isStorer) {
        zp0 = sc0_load_f32x4(zbuf + sb * 1024 + n0 + sc8);
        zp1 = sc0_load_f32x4(zbuf + sb * 1024 + n0 + sc8 + 4);
      }

      s16x8 ah[4][4], al[4][4];
#pragma unroll
      for (int ks = 0; ks < 4; ++ks)
#pragma unroll
        for (int mi = 0; mi < 4; ++mi)
          ah[ks][mi] = sc0_load_b128(s2 + (size_t)(lr + 16 * mi) * 2048 +
                                     (KB0 + ks * 32 + lg * 8));
#pragma unroll
      for (int ks = 0; ks < 4; ++ks)
#pragma unroll
        for (int mi = 0; mi < 4; ++mi)
          al[ks][mi] = sc0_load_b128(s2 + (size_t)(lr + 16 * mi) * 2048 +
                                     (1024 + KB0 + ks * 32 + lg * 8));

      f32x4 acc[4];
#pragma unroll
      for (int mi = 0; mi < 4; ++mi) {
        acc[mi][0] = 0.f; acc[mi][1] = 0.f; acc[mi][2] = 0.f; acc[mi][3] = 0.f;
      }

      asm volatile("s_waitcnt vmcnt(18)" ::: "memory");
      __builtin_amdgcn_sched_barrier(0);
      s16x8 bfv0[4];
#pragma unroll
      for (int ks = 0; ks < 4; ++ks) {
        int kp = KB0 + ks * 32 + lg * 8;
        bfv0[ks] = *(const s16x8*)(browp + ((kp * 2) ^ bswz));
#pragma unroll
        for (int mi = 0; mi < 4; ++mi)
          acc[mi] = __builtin_amdgcn_mfma_f32_16x16x32_bf16(ah[ks][mi], bfv0[ks],
                                                            acc[mi], 0, 0, 0);
      }
#pragma unroll
      for (int ks = 0; ks < 4; ++ks) {
        int kp = KB0 + ks * 32 + lg * 8;
        s16x8 bfv = *(const s16x8*)(browp + (((1024 + kp) * 2) ^ bswz));
#pragma unroll
        for (int mi = 0; mi < 4; ++mi)
          acc[mi] = __builtin_amdgcn_mfma_f32_16x16x32_bf16(ah[ks][mi], bfv,
                                                            acc[mi], 0, 0, 0);
      }
      vm_drain();
      __builtin_amdgcn_sched_barrier(0);
#pragma unroll
      for (int ks = 0; ks < 4; ++ks)
#pragma unroll
        for (int mi = 0; mi < 4; ++mi)
          acc[mi] = __builtin_amdgcn_mfma_f32_16x16x32_bf16(al[ks][mi], bfv0[ks],
                                                            acc[mi], 0, 0, 0);
#pragma unroll
      for (int mi = 0; mi < 4; ++mi)
#pragma unroll
        for (int v = 0; v < 4; ++v)
          red[(w * 64 + mi * 16 + lg * 4 + v) * 17 + lr] = acc[mi][v];
      __syncthreads();

#pragma unroll
      for (int u = 0; u < 2; ++u) {
        int b = eb[u], c = ec[u];
        float s = 0.f;
#pragma unroll
        for (int q = 0; q < 8; ++q) s += red[(q * 64 + b) * 17 + c];
        sums[b * 17 + c] = s + xpre[u];
      }
      __syncthreads();

      if (isStorer) {
        int j = n0 + sc8;
        s16x8 hhi, hlo;
        f32x4 o0, o1;
#pragma unroll
        for (int q = 0; q < 8; ++q) {
          float pre = sums[sb * 17 + sc8 + q];
          float ht = tanhf(pre);
          float z = (q < 4) ? zp0[q] : zp1[q - 4];
          float hn = (1.f - z) * hreg8[q] + z * ht;
          hreg8[q] = hn;
          unsigned short hb = f2bf(hn);
          hhi[q] = (short)hb;
          hlo[q] = (short)f2bf(hn - bf2f(hb));
          if (q < 4) o0[q] = hn; else o1[q - 4] = hn;
        }
        sc_store_b128(h2 + sb * 2048 + j, hhi);
        sc_store_b128(h2 + sb * 2048 + 1024 + j, hlo);
        sc_store_f32x4(out + ((size_t)sb * T_ + t) * 1024 + j, o0);
        sc_store_f32x4(out + ((size_t)sb * T_ + t) * 1024 + j + 4, o1);
        if (t == T_ - 1) {
          sc_store_f32x4(out + (size_t)B_ * T_ * 1024 + sb * 1024 + j, o0);
          sc_store_f32x4(out + (size_t)B_ * T_ * 1024 + sb * 1024 + j + 4, o1);
        }
        if (tt == Tcc - 1) {
          sc_store_f32x4(h + sb * 1024 + j, o0);
          sc_store_f32x4(h + sb * 1024 + j + 4, o1);
        }
      }
      vm_drain();
      __syncthreads();
      if (tid == 0)
        __hip_atomic_fetch_add(cntB + (size_t)(bid & 7) * FSTR, 1u,
                               __ATOMIC_RELAXED, __HIP_MEMORY_SCOPE_AGENT);
    }
  }
}

extern "C" void kernel_launch(void* const* d_in, const int* in_sizes, int n_in,
                              void* d_out, int out_size, void* d_ws, size_t ws_size,
                              hipStream_t stream) {
  const float* x  = (const float*)d_in[0];
  const float* h0 = (const float*)d_in[1];
  const float* Wz = (const float*)d_in[2];
  const float* bz = (const float*)d_in[3];
  const float* Uz = (const float*)d_in[4];
  const float* Wr = (const float*)d_in[5];
  const float* br = (const float*)d_in[6];
  const float* Ur = (const float*)d_in[7];
  const float* Wh = (const float*)d_in[8];
  const float* bh = (const float*)d_in[9];
  const float* Uh = (const float*)d_in[10];
  float* out = (float*)d_out;

  uint8_t* ws = (uint8_t*)d_ws;
  uint16_t* W2    = (uint16_t*)(ws + 0);          // [3072][1536] bf16
  float*    hbuf  = (float*)   (ws + 9437184);    // [64][1024]
  uint16_t* h2    = (uint16_t*)(ws + 9699328);    // [64][2048]
  uint16_t* s2    = (uint16_t*)(ws + 9961472);    // [64][2048]
  float*    zbuf  = (float*)   (ws + 10223616);   // [64][1024]
  unsigned* cntA  = (unsigned*)(ws + 10485760);   // 8 x 256B
  unsigned* cntB  = (unsigned*)(ws + 10489856);   // 8 x 256B
  float*    XP    = (float*)   (ws + 10493952);   // [Tc][3][64][1024] fp32

  hipMemsetAsync((void*)cntA, 0, 8192, stream);

  k_split<<<512, 256, 0, stream>>>(Wz, W2, 9, 1024 * 512);
  k_split<<<512, 256, 0, stream>>>(Wr, W2 + (size_t)1024 * 1536, 9, 1024 * 512);
  k_split<<<512, 256, 0, stream>>>(Wh, W2 + (size_t)2048 * 1536, 9, 1024 * 512);
  k_init<<<64, 256, 0, stream>>>(h0, hbuf, h2);

  size_t avail = (ws_size > 10493952u) ? (ws_size - 10493952u) : 0u;
  long long tcl = (long long)(avail / 786432u);
  int Tc = (tcl > 512) ? 512 : (int)tcl;
  Tc &= ~1;
  if (Tc < 2) Tc = 2;

  for (int t0 = 0; t0 < T_; t0 += Tc) {
    int Tcc = (Tc < T_ - t0) ? Tc : (T_ - t0);
    int MT = (B_ * Tcc) / 128;
    k_proj<<<MT * 24, 256, 0, stream>>>(x, W2, bz, br, bh, XP, t0, Tcc, MT);

    int t0v = t0, tccv = Tcc;
    void* args[] = {(void*)&Uz, (void*)&Ur, (void*)&Uh, (void*)&XP,
                    (void*)&t0v, (void*)&tccv, (void*)&hbuf, (void*)&h2,
                    (void*)&s2, (void*)&zbuf, (void*)&out,
                    (void*)&cntA, (void*)&cntB};
    hipLaunchCooperativeKernel((void*)k_recur, dim3(NWG), dim3(512),
                               args, 0, stream);
  }
}